// Round 6
// baseline (461.592 us; speedup 1.0000x reference)
//
#include <hip/hip_runtime.h>
#include <stdint.h>

typedef __attribute__((ext_vector_type(4))) float f32x4;
typedef __attribute__((ext_vector_type(8))) short short8;
typedef __attribute__((ext_vector_type(4))) unsigned short u16x4;

#define MFMA16(a, b, c) __builtin_amdgcn_mfma_f32_16x16x32_bf16((a), (b), (c), 0, 0, 0)

__device__ __forceinline__ unsigned short f2bf(float f) {
  unsigned int x = __float_as_uint(f);
  return (unsigned short)((x + 0x7fffu + ((x >> 16) & 1u)) >> 16);
}
__device__ __forceinline__ float bf2f(unsigned short u) {
  return __uint_as_float(((unsigned int)u) << 16);
}

__device__ __forceinline__ void gl2lds16(const void* g, void* l) {
  __builtin_amdgcn_global_load_lds((const __attribute__((address_space(1))) void*)g,
                                   (__attribute__((address_space(3))) void*)l, 16, 0, 0);
}

__device__ __forceinline__ void load8cv(const float* __restrict__ s, void* d) {
  const f32x4* p = (const f32x4*)s;
  f32x4 a = p[0], b = p[1];
  short8 t;
  t[0] = (short)f2bf(a[0]); t[1] = (short)f2bf(a[1]);
  t[2] = (short)f2bf(a[2]); t[3] = (short)f2bf(a[3]);
  t[4] = (short)f2bf(b[0]); t[5] = (short)f2bf(b[1]);
  t[6] = (short)f2bf(b[2]); t[7] = (short)f2bf(b[3]);
  *(short8*)d = t;
}

__device__ __forceinline__ void storec(float* p, float v) { *p = v; }
__device__ __forceinline__ void storec(unsigned short* p, float v) { *p = f2bf(v); }

#define BAR_V4 asm volatile("s_waitcnt vmcnt(4)\ns_barrier" ::: "memory")
#define BAR_V0 asm volatile("s_waitcnt vmcnt(0)\ns_barrier" ::: "memory")
#define BAR_RAW asm volatile("s_barrier" ::: "memory")

// ---------------------------------------------------------------------------
__global__ __launch_bounds__(256) void cast_weights(const float* __restrict__ wq,
                                                    const float* __restrict__ wk,
                                                    const float* __restrict__ wv,
                                                    const float* __restrict__ wo,
                                                    unsigned short* __restrict__ dst) {
  int i = blockIdx.x * 256 + threadIdx.x;
  int which = i >> 17;
  int off = (i & 131071) * 8;
  const float* src = which == 0 ? wq : which == 1 ? wk : which == 2 ? wv : wo;
  load8cv(src + off, dst + (size_t)which * 1048576 + off);
}

// ---------------------------------------------------------------------------
// C[M][N] = A[M][K] @ Bt[N][K]^T, epilogue (acc+bias)*oscale. 128x64 tile,
// BK=64, 4 waves (2x2). (unchanged from round 4 — working baseline)
// ---------------------------------------------------------------------------
template <typename TA, typename TOUT>
__global__ __launch_bounds__(256) void gemm_bias(const TA* __restrict__ A,
                                                 const unsigned short* __restrict__ Bt,
                                                 const float* __restrict__ bias,
                                                 TOUT* __restrict__ C,
                                                 int M, int N, int K, float oscale) {
  __shared__ __align__(16) char lds[24576];
  char* As = lds;
  char* Bs = lds + 16384;
  const int tid = threadIdx.x;
  const int lane = tid & 63;
  const int wv = tid >> 6;
  const int g = lane >> 4, r = lane & 15;
  const int wm = wv >> 1, wn = wv & 1;
  const int m0 = blockIdx.y * 128, n0 = blockIdx.x * 64;

  f32x4 acc[4][2];
#pragma unroll
  for (int m = 0; m < 4; ++m)
#pragma unroll
    for (int n = 0; n < 2; ++n) acc[m][n] = (f32x4){0.f, 0.f, 0.f, 0.f};

  for (int k0 = 0; k0 < K; k0 += 64) {
    __syncthreads();
#pragma unroll
    for (int i = 0; i < 2; ++i) {
      int c = (wv * 2 + i) * 64 + lane;
      int row = c >> 3;
      gl2lds16(Bt + (size_t)(n0 + row) * K + k0 + (c & 7) * 8, Bs + (wv * 2 + i) * 1024);
    }
    if constexpr (sizeof(TA) == 2) {
#pragma unroll
      for (int i = 0; i < 4; ++i) {
        int c = (wv * 4 + i) * 64 + lane;
        int row = c >> 3;
        gl2lds16(A + (size_t)(m0 + row) * K + k0 + (c & 7) * 8, As + (wv * 4 + i) * 1024);
      }
    } else {
#pragma unroll
      for (int i = 0; i < 4; ++i) {
        int c = tid + i * 256;
        int row = c >> 3, e = (c & 7) * 8;
        load8cv(A + (size_t)(m0 + row) * K + k0 + e, As + c * 16);
      }
    }
    __syncthreads();
#pragma unroll
    for (int kk = 0; kk < 2; ++kk) {
      short8 af[4], bq[2];
#pragma unroll
      for (int m = 0; m < 4; ++m)
        af[m] = *(const short8*)(As + (wm * 64 + m * 16 + r) * 128 + kk * 64 + g * 16);
#pragma unroll
      for (int n = 0; n < 2; ++n)
        bq[n] = *(const short8*)(Bs + (wn * 32 + n * 16 + r) * 128 + kk * 64 + g * 16);
#pragma unroll
      for (int m = 0; m < 4; ++m)
#pragma unroll
        for (int n = 0; n < 2; ++n) acc[m][n] = MFMA16(af[m], bq[n], acc[m][n]);
    }
  }

#pragma unroll
  for (int n = 0; n < 2; ++n) {
    int col = n0 + wn * 32 + n * 16 + r;
    float bv = bias[col];
#pragma unroll
    for (int m = 0; m < 4; ++m) {
#pragma unroll
      for (int i = 0; i < 4; ++i) {
        int rowg = m0 + wm * 64 + m * 16 + 4 * g + i;
        storec(C + (size_t)rowg * N + col, (acc[m][n][i] + bv) * oscale);
      }
    }
  }
}

// ---------------------------------------------------------------------------
__global__ __launch_bounds__(256) void transpose_v(const unsigned short* __restrict__ V,
                                                   unsigned short* __restrict__ Vt) {
  int t = blockIdx.x * 256 + threadIdx.x;
  int d = t & 63;
  int sc = (t >> 6) & 255;
  int bh = t >> 14;
  int b = bh >> 4, h = bh & 15;
  unsigned short vals[8];
#pragma unroll
  for (int j = 0; j < 8; ++j)
    vals[j] = V[(size_t)(b * 2048 + sc * 8 + j) * 1024 + h * 64 + d];
  *(short8*)&Vt[((size_t)bh * 64 + d) * 2048 + sc * 8] = *(short8*)vals;
}

// ---------------------------------------------------------------------------
// Fused attention v5. QBLK=128 (4 waves x 32 q-rows), 512 blocks.
// SWAPPED QK^T: s = mfma(K_frag, Q_frag) -> S^T layout: lane (g,r) holds
// S[q = r][k = 16*ct + 4g + i] — 4 CONSECUTIVE k per reg quad. This makes
// P-writes packed ds_write_b64 (8/tile vs 32 scalar), and l a per-lane
// scalar (reduce = shfl_xor 16,32).
// LDS: 2x16KB K/V dbuf + 4x2KB pbuf = 40KB -> 4 blocks/CU. Counted-vmcnt
// double-buffer pipeline as round 4.
// ---------------------------------------------------------------------------
__global__ __launch_bounds__(256, 4) void attn_fused(const unsigned short* __restrict__ Q,
                                                     const unsigned short* __restrict__ K,
                                                     const unsigned short* __restrict__ Vt,
                                                     float* __restrict__ attn,
                                                     unsigned short* __restrict__ O) {
  __shared__ __align__(16) char lds[40960];
  const int tid = threadIdx.x;
  const int lane = tid & 63;
  const int wv = tid >> 6;
  const int g = lane >> 4, r = lane & 15;
  // XCD-chunked bijective swizzle (512 = 8*64)
  int nb = (blockIdx.x & 7) * 64 + (blockIdx.x >> 3);
  const int qt = nb & 15, bh = nb >> 4, h = bh & 15, b = bh >> 4;
  const int qloc = qt * 128 + wv * 32;
  const int qrow0 = b * 2048 + qloc;
  const unsigned short* Kbh = K + (size_t)b * 2048 * 1024 + h * 64;
  const unsigned short* Vbh = Vt + (size_t)bh * 64 * 2048;
  float* attn_bh = attn + (size_t)bh * 2048 * 2048;
  char* pb = lds + 32768 + wv * 2048;

  short8 qf[2][2];
#pragma unroll
  for (int qg = 0; qg < 2; ++qg)
#pragma unroll
    for (int kk = 0; kk < 2; ++kk)
      qf[qg][kk] = *(const short8*)&Q[(size_t)(qrow0 + qg * 16 + r) * 1024 + h * 64 + kk * 32 + g * 8];

#define P1_ISSUE(bb, ktt)                                                      \
  do {                                                                         \
    _Pragma("unroll") for (int i_ = 0; i_ < 4; ++i_) {                         \
      int c_ = (wv * 4 + i_) * 64 + lane;                                      \
      int kr_ = c_ >> 3;                                                       \
      int scb_ = ((c_ & 7) * 16) ^ ((kr_ & 7) << 4);                           \
      gl2lds16(Kbh + (size_t)((ktt) + kr_) * 1024 + (scb_ >> 1),               \
               (bb) + (wv * 4 + i_) * 1024);                                   \
    }                                                                          \
  } while (0)
#define P2_ISSUE(bb, ktt)                                                      \
  do {                                                                         \
    _Pragma("unroll") for (int i_ = 0; i_ < 4; ++i_) {                         \
      int c_ = (wv * 4 + i_) * 64 + lane;                                      \
      int kr_ = (c_ >> 3) & 63;                                                \
      int scb_ = ((c_ & 7) * 16) ^ ((kr_ & 7) << 4);                           \
      const unsigned short* src_ =                                             \
          (c_ < 512) ? (Kbh + (size_t)((ktt) + kr_) * 1024 + (scb_ >> 1))      \
                     : (Vbh + (size_t)kr_ * 2048 + (ktt) + (scb_ >> 1));       \
      gl2lds16(src_, (bb) + (wv * 4 + i_) * 1024);                             \
    }                                                                          \
  } while (0)

  // ---------------- pass 1: per-lane scalar exp-sums, KVBLK=128 ------------
  float lrow[2] = {0.f, 0.f};
  int cur = 0;
  P1_ISSUE(lds, 0);
  for (int t = 0; t < 16; ++t) {
    char* bcur = lds + (cur << 14);
    char* bnxt = lds + ((cur ^ 1) << 14);
    if (t < 15) {
      P1_ISSUE(bnxt, (t + 1) * 128);
      BAR_V4;
    } else {
      BAR_V0;
    }
#pragma unroll
    for (int ct = 0; ct < 8; ++ct) {
      int row = ct * 16 + r;
      int sw = (row & 7) << 4;
      short8 kf0 = *(const short8*)(bcur + ((row * 128 + g * 16) ^ sw));
      short8 kf1 = *(const short8*)(bcur + ((row * 128 + 64 + g * 16) ^ sw));
#pragma unroll
      for (int qg = 0; qg < 2; ++qg) {
        f32x4 s = (f32x4){0.f, 0.f, 0.f, 0.f};
        s = MFMA16(kf0, qf[qg][0], s);
        s = MFMA16(kf1, qf[qg][1], s);
        lrow[qg] += __expf(s[0]) + __expf(s[1]) + __expf(s[2]) + __expf(s[3]);
      }
    }
    BAR_RAW;
    cur ^= 1;
  }
  float linv[2];
#pragma unroll
  for (int qg = 0; qg < 2; ++qg) {
    float l = lrow[qg];
    l += __shfl_xor(l, 16);
    l += __shfl_xor(l, 32);
    linv[qg] = 1.0f / l;
  }

  // ---------------- pass 2: packed P + coalesced store + PV ----------------
  f32x4 oacc[2][4];
#pragma unroll
  for (int qg = 0; qg < 2; ++qg)
#pragma unroll
    for (int i = 0; i < 4; ++i) oacc[qg][i] = (f32x4){0.f, 0.f, 0.f, 0.f};

  cur = 0;
  P2_ISSUE(lds, 0);
  const int swr = (r & 7) << 4;
  for (int t = 0; t < 32; ++t) {
    char* bcur = lds + (cur << 14);
    char* bnxt = lds + ((cur ^ 1) << 14);
    int kt = t * 64;
    if (t < 31) {
      P2_ISSUE(bnxt, kt + 64);
      BAR_V4;
    } else {
      BAR_V0;
    }
    // swapped QK^T: s[qg][ct][i] = S[q=r][k=16ct+4g+i]
    f32x4 s[2][4];
#pragma unroll
    for (int ct = 0; ct < 4; ++ct) {
      int row = ct * 16 + r;
      int sw = (row & 7) << 4;
      short8 kf0 = *(const short8*)(bcur + ((row * 128 + g * 16) ^ sw));
      short8 kf1 = *(const short8*)(bcur + ((row * 128 + 64 + g * 16) ^ sw));
#pragma unroll
      for (int qg = 0; qg < 2; ++qg) {
        f32x4 acc0 = (f32x4){0.f, 0.f, 0.f, 0.f};
        acc0 = MFMA16(kf0, qf[qg][0], acc0);
        s[qg][ct] = MFMA16(kf1, qf[qg][1], acc0);
      }
    }
#pragma unroll
    for (int qg = 0; qg < 2; ++qg) {
      // packed P-writes: row r, 4 consecutive k per write (b64)
#pragma unroll
      for (int ct = 0; ct < 4; ++ct) {
        u16x4 pk;
        pk[0] = f2bf(__expf(s[qg][ct][0]) * linv[qg]);
        pk[1] = f2bf(__expf(s[qg][ct][1]) * linv[qg]);
        pk[2] = f2bf(__expf(s[qg][ct][2]) * linv[qg]);
        pk[3] = f2bf(__expf(s[qg][ct][3]) * linv[qg]);
        *(u16x4*)(pb + ((r * 128 + (ct * 16 + 4 * g) * 2) ^ swr)) = pk;
      }
      // coalesced attn store: 4 insts x (4 rows x 256B contiguous)
#pragma unroll
      for (int rep = 0; rep < 4; ++rep) {
        int row = rep * 4 + g;
        const unsigned short* ps =
            (const unsigned short*)(pb + ((row * 128 + r * 8) ^ ((row & 7) << 4)));
        f32x4 o4;
        o4[0] = bf2f(ps[0]); o4[1] = bf2f(ps[1]);
        o4[2] = bf2f(ps[2]); o4[3] = bf2f(ps[3]);
        *(f32x4*)&attn_bh[(size_t)(qloc + qg * 16 + row) * 2048 + kt + r * 4] = o4;
      }
      // PV: oacc[qg] += P[16x64] @ V[64x64]
#pragma unroll
      for (int kk2 = 0; kk2 < 2; ++kk2) {
        short8 pa = *(const short8*)(pb + ((r * 128 + kk2 * 64 + g * 16) ^ swr));
#pragma unroll
        for (int ct2 = 0; ct2 < 4; ++ct2) {
          int vrow = ct2 * 16 + r;
          short8 vf = *(const short8*)(bcur + 8192 +
                                       ((vrow * 128 + kk2 * 64 + g * 16) ^ ((vrow & 7) << 4)));
          oacc[qg][ct2] = MFMA16(pa, vf, oacc[qg][ct2]);
        }
      }
    }
    BAR_RAW;
    cur ^= 1;
  }
#pragma unroll
  for (int qg = 0; qg < 2; ++qg)
#pragma unroll
    for (int ct2 = 0; ct2 < 4; ++ct2)
#pragma unroll
      for (int i = 0; i < 4; ++i)
        O[(size_t)(qrow0 + qg * 16 + 4 * g + i) * 1024 + h * 64 + ct2 * 16 + r] =
            f2bf(oacc[qg][ct2][i]);
#undef P1_ISSUE
#undef P2_ISSUE
}

// ---------------------------------------------------------------------------
extern "C" void kernel_launch(void* const* d_in, const int* in_sizes, int n_in,
                              void* d_out, int out_size, void* d_ws, size_t ws_size,
                              hipStream_t stream) {
  const float* q_in = (const float*)d_in[0];
  const float* k_in = (const float*)d_in[1];
  const float* v_in = (const float*)d_in[2];
  const float* wq = (const float*)d_in[3];
  const float* bq = (const float*)d_in[4];
  const float* wk = (const float*)d_in[5];
  const float* bk = (const float*)d_in[6];
  const float* wv = (const float*)d_in[7];
  const float* bv = (const float*)d_in[8];
  const float* wo = (const float*)d_in[9];
  const float* bo = (const float*)d_in[10];

  char* ws = (char*)d_ws;
  const size_t MB8 = 8ull * 1024 * 1024;
  unsigned short* W16 = (unsigned short*)(ws);
  unsigned short* Q16 = (unsigned short*)(ws + MB8);
  unsigned short* K16 = (unsigned short*)(ws + 2 * MB8);
  unsigned short* V16 = (unsigned short*)(ws + 3 * MB8);
  unsigned short* Vt  = (unsigned short*)(ws + 4 * MB8);
  unsigned short* O16 = (unsigned short*)(ws + 3 * MB8);  // alias V16

  float* out = (float*)d_out;
  float* attn = out + 4194304ull;

  dim3 blk(256);
  dim3 gproj(16, 32);
  cast_weights<<<dim3(2048), blk, 0, stream>>>(wq, wk, wv, wo, W16);
  gemm_bias<float, unsigned short><<<gproj, blk, 0, stream>>>(q_in, W16, bq, Q16, 4096, 1024, 1024, 0.125f);
  gemm_bias<float, unsigned short><<<gproj, blk, 0, stream>>>(k_in, W16 + 1048576, bk, K16, 4096, 1024, 1024, 1.0f);
  gemm_bias<float, unsigned short><<<gproj, blk, 0, stream>>>(v_in, W16 + 2097152, bv, V16, 4096, 1024, 1024, 1.0f);
  transpose_v<<<dim3(2048), blk, 0, stream>>>(V16, Vt);
  attn_fused<<<dim3(512), blk, 0, stream>>>(Q16, K16, Vt, attn, O16);
  gemm_bias<unsigned short, float><<<gproj, blk, 0, stream>>>(O16, W16 + 3145728, bo, out, 4096, 1024, 1024, 1.0f);
}

// Round 7
// 321.234 us; speedup vs baseline: 1.4369x; 1.4369x over previous
//
#include <hip/hip_runtime.h>
#include <stdint.h>

typedef __attribute__((ext_vector_type(4))) float f32x4;
typedef __attribute__((ext_vector_type(8))) short short8;
typedef __attribute__((ext_vector_type(2))) unsigned int u32x2;

#define MFMA16(a, b, c) __builtin_amdgcn_mfma_f32_16x16x32_bf16((a), (b), (c), 0, 0, 0)

__device__ __forceinline__ unsigned short f2bf(float f) {
  unsigned int x = __float_as_uint(f);
  return (unsigned short)((x + 0x7fffu + ((x >> 16) & 1u)) >> 16);
}

// packed f32x2 -> bf16x2 (single VALU op, T12)
__device__ __forceinline__ unsigned int cvtpk(float lo, float hi) {
  unsigned int d;
  asm("v_cvt_pk_bf16_f32 %0, %1, %2" : "=v"(d) : "v"(lo), "v"(hi));
  return d;
}

__device__ __forceinline__ void gl2lds16(const void* g, void* l) {
  __builtin_amdgcn_global_load_lds((const __attribute__((address_space(1))) void*)g,
                                   (__attribute__((address_space(3))) void*)l, 16, 0, 0);
}

__device__ __forceinline__ void load8cv(const float* __restrict__ s, void* d) {
  const f32x4* p = (const f32x4*)s;
  f32x4 a = p[0], b = p[1];
  short8 t;
  t[0] = (short)f2bf(a[0]); t[1] = (short)f2bf(a[1]);
  t[2] = (short)f2bf(a[2]); t[3] = (short)f2bf(a[3]);
  t[4] = (short)f2bf(b[0]); t[5] = (short)f2bf(b[1]);
  t[6] = (short)f2bf(b[2]); t[7] = (short)f2bf(b[3]);
  *(short8*)d = t;
}

#define BAR_V4 asm volatile("s_waitcnt vmcnt(4)\ns_barrier" ::: "memory")
#define BAR_V0 asm volatile("s_waitcnt vmcnt(0)\ns_barrier" ::: "memory")
#define BAR_RAW asm volatile("s_barrier" ::: "memory")

// ---------------------------------------------------------------------------
__global__ __launch_bounds__(256) void cast_weights(const float* __restrict__ wq,
                                                    const float* __restrict__ wk,
                                                    const float* __restrict__ wv,
                                                    const float* __restrict__ wo,
                                                    unsigned short* __restrict__ dst) {
  int i = blockIdx.x * 256 + threadIdx.x;
  int which = i >> 17;
  int off = (i & 131071) * 8;
  const float* src = which == 0 ? wq : which == 1 ? wk : which == 2 ? wv : wo;
  load8cv(src + off, dst + (size_t)which * 1048576 + off);
}

// ---------------------------------------------------------------------------
// Fused QKV projection: grid.z selects {Q,K,V}. 128x64 tile, BK=64, 4 waves.
// f32 A reg-staged w/ convert; bf16 W via global_load_lds. (round-4 body)
// ---------------------------------------------------------------------------
__global__ __launch_bounds__(256) void qkv_proj(const float* __restrict__ q_in,
                                                const float* __restrict__ k_in,
                                                const float* __restrict__ v_in,
                                                const unsigned short* __restrict__ W16,
                                                const float* __restrict__ bq,
                                                const float* __restrict__ bk,
                                                const float* __restrict__ bv,
                                                unsigned short* __restrict__ Q16,
                                                unsigned short* __restrict__ K16,
                                                unsigned short* __restrict__ V16) {
  const int z = blockIdx.z;
  const float* A = z == 0 ? q_in : z == 1 ? k_in : v_in;
  const unsigned short* Bt = W16 + (size_t)z * 1048576;
  const float* bias = z == 0 ? bq : z == 1 ? bk : bv;
  unsigned short* C = z == 0 ? Q16 : z == 1 ? K16 : V16;
  const float oscale = z == 0 ? 0.125f : 1.0f;
  const int K = 1024, N = 1024;

  __shared__ __align__(16) char lds[24576];
  char* As = lds;
  char* Bs = lds + 16384;
  const int tid = threadIdx.x;
  const int lane = tid & 63;
  const int wv = tid >> 6;
  const int g = lane >> 4, r = lane & 15;
  const int wm = wv >> 1, wn = wv & 1;
  const int m0 = blockIdx.y * 128, n0 = blockIdx.x * 64;

  f32x4 acc[4][2];
#pragma unroll
  for (int m = 0; m < 4; ++m)
#pragma unroll
    for (int n = 0; n < 2; ++n) acc[m][n] = (f32x4){0.f, 0.f, 0.f, 0.f};

  for (int k0 = 0; k0 < K; k0 += 64) {
    __syncthreads();
#pragma unroll
    for (int i = 0; i < 2; ++i) {
      int c = (wv * 2 + i) * 64 + lane;
      int row = c >> 3;
      gl2lds16(Bt + (size_t)(n0 + row) * K + k0 + (c & 7) * 8, Bs + (wv * 2 + i) * 1024);
    }
#pragma unroll
    for (int i = 0; i < 4; ++i) {
      int c = tid + i * 256;
      int row = c >> 3, e = (c & 7) * 8;
      load8cv(A + (size_t)(m0 + row) * K + k0 + e, As + c * 16);
    }
    __syncthreads();
#pragma unroll
    for (int kk = 0; kk < 2; ++kk) {
      short8 af[4], bfr[2];
#pragma unroll
      for (int m = 0; m < 4; ++m)
        af[m] = *(const short8*)(As + (wm * 64 + m * 16 + r) * 128 + kk * 64 + g * 16);
#pragma unroll
      for (int n = 0; n < 2; ++n)
        bfr[n] = *(const short8*)(Bs + (wn * 32 + n * 16 + r) * 128 + kk * 64 + g * 16);
#pragma unroll
      for (int m = 0; m < 4; ++m)
#pragma unroll
        for (int n = 0; n < 2; ++n) acc[m][n] = MFMA16(af[m], bfr[n], acc[m][n]);
    }
  }

#pragma unroll
  for (int n = 0; n < 2; ++n) {
    int col = n0 + wn * 32 + n * 16 + r;
    float bv_ = bias[col];
#pragma unroll
    for (int m = 0; m < 4; ++m)
#pragma unroll
      for (int i = 0; i < 4; ++i) {
        int rowg = m0 + wm * 64 + m * 16 + 4 * g + i;
        C[(size_t)rowg * N + col] = f2bf((acc[m][n][i] + bv_) * oscale);
      }
  }
}

// ---------------------------------------------------------------------------
// O-projection: bf16 A via global_load_lds, f32 out. (round-4 body)
// ---------------------------------------------------------------------------
__global__ __launch_bounds__(256) void o_proj(const unsigned short* __restrict__ A,
                                              const unsigned short* __restrict__ Bt,
                                              const float* __restrict__ bias,
                                              float* __restrict__ C) {
  const int K = 1024, N = 1024;
  __shared__ __align__(16) char lds[24576];
  char* As = lds;
  char* Bs = lds + 16384;
  const int tid = threadIdx.x;
  const int lane = tid & 63;
  const int wv = tid >> 6;
  const int g = lane >> 4, r = lane & 15;
  const int wm = wv >> 1, wn = wv & 1;
  const int m0 = blockIdx.y * 128, n0 = blockIdx.x * 64;

  f32x4 acc[4][2];
#pragma unroll
  for (int m = 0; m < 4; ++m)
#pragma unroll
    for (int n = 0; n < 2; ++n) acc[m][n] = (f32x4){0.f, 0.f, 0.f, 0.f};

  for (int k0 = 0; k0 < K; k0 += 64) {
    __syncthreads();
#pragma unroll
    for (int i = 0; i < 2; ++i) {
      int c = (wv * 2 + i) * 64 + lane;
      int row = c >> 3;
      gl2lds16(Bt + (size_t)(n0 + row) * K + k0 + (c & 7) * 8, Bs + (wv * 2 + i) * 1024);
    }
#pragma unroll
    for (int i = 0; i < 4; ++i) {
      int c = (wv * 4 + i) * 64 + lane;
      int row = c >> 3;
      gl2lds16(A + (size_t)(m0 + row) * K + k0 + (c & 7) * 8, As + (wv * 4 + i) * 1024);
    }
    __syncthreads();
#pragma unroll
    for (int kk = 0; kk < 2; ++kk) {
      short8 af[4], bfr[2];
#pragma unroll
      for (int m = 0; m < 4; ++m)
        af[m] = *(const short8*)(As + (wm * 64 + m * 16 + r) * 128 + kk * 64 + g * 16);
#pragma unroll
      for (int n = 0; n < 2; ++n)
        bfr[n] = *(const short8*)(Bs + (wn * 32 + n * 16 + r) * 128 + kk * 64 + g * 16);
#pragma unroll
      for (int m = 0; m < 4; ++m)
#pragma unroll
        for (int n = 0; n < 2; ++n) acc[m][n] = MFMA16(af[m], bfr[n], acc[m][n]);
    }
  }

#pragma unroll
  for (int n = 0; n < 2; ++n) {
    int col = n0 + wn * 32 + n * 16 + r;
    float bv_ = bias[col];
#pragma unroll
    for (int m = 0; m < 4; ++m)
#pragma unroll
      for (int i = 0; i < 4; ++i) {
        int rowg = m0 + wm * 64 + m * 16 + 4 * g + i;
        C[(size_t)rowg * N + col] = acc[m][n][i] + bv_;
      }
  }
}

// ---------------------------------------------------------------------------
__global__ __launch_bounds__(256) void transpose_v(const unsigned short* __restrict__ V,
                                                   unsigned short* __restrict__ Vt) {
  int t = blockIdx.x * 256 + threadIdx.x;
  int d = t & 63;
  int sc = (t >> 6) & 255;
  int bh = t >> 14;
  int b = bh >> 4, h = bh & 15;
  unsigned short vals[8];
#pragma unroll
  for (int j = 0; j < 8; ++j)
    vals[j] = V[(size_t)(b * 2048 + sc * 8 + j) * 1024 + h * 64 + d];
  *(short8*)&Vt[((size_t)bh * 64 + d) * 2048 + sc * 8] = *(short8*)vals;
}

// ---------------------------------------------------------------------------
// Fused attention v7 = round-4 geometry (QBLK=64, 1024 blocks, 4 blocks/CU)
// + swapped QK^T (verified r6): lane(g,r) holds S[q=r][k=16ct+4g+i]
// + direct f32x4 attention stores from registers (no LDS round trip)
// + normalization folded into MFMA C-init (c = -ln(l), p = expf(s) done)
// + cvt_pk packed bf16 P-writes for the PV path (4x ds_write_b64/tile).
// ---------------------------------------------------------------------------
__global__ __launch_bounds__(256, 4) void attn_fused(const unsigned short* __restrict__ Q,
                                                     const unsigned short* __restrict__ K,
                                                     const unsigned short* __restrict__ Vt,
                                                     float* __restrict__ attn,
                                                     unsigned short* __restrict__ O) {
  __shared__ __align__(16) char lds[40960];  // dbuf 2x16KB | pbuf 4x2KB
  const int tid = threadIdx.x;
  const int lane = tid & 63;
  const int wv = tid >> 6;
  const int g = lane >> 4, r = lane & 15;
  // XCD-chunked bijective swizzle (1024 = 8*128)
  int nb = (blockIdx.x & 7) * 128 + (blockIdx.x >> 3);
  const int qt = nb & 31, bh = nb >> 5, h = bh & 15, b = bh >> 4;
  const int qloc = qt * 64 + wv * 16;
  const int qrow0 = b * 2048 + qloc;
  const unsigned short* Kbh = K + (size_t)b * 2048 * 1024 + h * 64;
  const unsigned short* Vbh = Vt + (size_t)bh * 64 * 2048;
  float* attn_bh = attn + (size_t)bh * 2048 * 2048;
  char* pb = lds + 32768 + wv * 2048;
  const int swr = (r & 7) << 4;

  short8 qf[2];
#pragma unroll
  for (int kk = 0; kk < 2; ++kk)
    qf[kk] = *(const short8*)&Q[(size_t)(qrow0 + r) * 1024 + h * 64 + kk * 32 + g * 8];

#define P1_ISSUE(bb, ktt)                                                      \
  do {                                                                         \
    _Pragma("unroll") for (int i_ = 0; i_ < 4; ++i_) {                         \
      int c_ = (wv * 4 + i_) * 64 + lane;                                      \
      int kr_ = c_ >> 3;                                                       \
      int scb_ = ((c_ & 7) * 16) ^ ((kr_ & 7) << 4);                           \
      gl2lds16(Kbh + (size_t)((ktt) + kr_) * 1024 + (scb_ >> 1),               \
               (bb) + (wv * 4 + i_) * 1024);                                   \
    }                                                                          \
  } while (0)
#define P2_ISSUE(bb, ktt)                                                      \
  do {                                                                         \
    _Pragma("unroll") for (int i_ = 0; i_ < 4; ++i_) {                         \
      int c_ = (wv * 4 + i_) * 64 + lane;                                      \
      int kr_ = (c_ >> 3) & 63;                                                \
      int scb_ = ((c_ & 7) * 16) ^ ((kr_ & 7) << 4);                           \
      const unsigned short* src_ =                                             \
          (c_ < 512) ? (Kbh + (size_t)((ktt) + kr_) * 1024 + (scb_ >> 1))      \
                     : (Vbh + (size_t)kr_ * 2048 + (ktt) + (scb_ >> 1));       \
      gl2lds16(src_, (bb) + (wv * 4 + i_) * 1024);                             \
    }                                                                          \
  } while (0)

  // ---------------- pass 1: per-lane exp-sum (swapped layout), KVBLK=128 ----
  float lrow = 0.f;
  int cur = 0;
  P1_ISSUE(lds, 0);
  for (int t = 0; t < 16; ++t) {
    char* bcur = lds + (cur << 14);
    char* bnxt = lds + ((cur ^ 1) << 14);
    if (t < 15) {
      P1_ISSUE(bnxt, (t + 1) * 128);
      BAR_V4;
    } else {
      BAR_V0;
    }
#pragma unroll
    for (int ct = 0; ct < 8; ++ct) {
      int row = ct * 16 + r;
      int sw = (row & 7) << 4;
      short8 kf0 = *(const short8*)(bcur + ((row * 128 + g * 16) ^ sw));
      short8 kf1 = *(const short8*)(bcur + ((row * 128 + 64 + g * 16) ^ sw));
      f32x4 s = (f32x4){0.f, 0.f, 0.f, 0.f};
      s = MFMA16(kf0, qf[0], s);
      s = MFMA16(kf1, qf[1], s);
      lrow += (__expf(s[0]) + __expf(s[1])) + (__expf(s[2]) + __expf(s[3]));
    }
    BAR_RAW;
    cur ^= 1;
  }
  {
    lrow += __shfl_xor(lrow, 16);
    lrow += __shfl_xor(lrow, 32);
  }
  const float negml = -__logf(lrow);
  const f32x4 cinit = (f32x4){negml, negml, negml, negml};

  // ---------------- pass 2: direct store + PV, KVBLK=64 --------------------
  f32x4 oacc[4];
#pragma unroll
  for (int i = 0; i < 4; ++i) oacc[i] = (f32x4){0.f, 0.f, 0.f, 0.f};

  float* arow = attn_bh + (size_t)(qloc + r) * 2048 + 4 * g;
  cur = 0;
  P2_ISSUE(lds, 0);
  for (int t = 0; t < 32; ++t) {
    char* bcur = lds + (cur << 14);
    char* bnxt = lds + ((cur ^ 1) << 14);
    int kt = t * 64;
    if (t < 31) {
      P2_ISSUE(bnxt, kt + 64);
      BAR_V4;
    } else {
      BAR_V0;
    }
    // QK^T (C-init = -ln l) -> p = expf(s) already normalized
#pragma unroll
    for (int ct = 0; ct < 4; ++ct) {
      int row = ct * 16 + r;
      int sw = (row & 7) << 4;
      short8 kf0 = *(const short8*)(bcur + ((row * 128 + g * 16) ^ sw));
      short8 kf1 = *(const short8*)(bcur + ((row * 128 + 64 + g * 16) ^ sw));
      f32x4 s = MFMA16(kf0, qf[0], cinit);
      s = MFMA16(kf1, qf[1], s);
      f32x4 p;
      p[0] = __expf(s[0]); p[1] = __expf(s[1]);
      p[2] = __expf(s[2]); p[3] = __expf(s[3]);
      // direct coalesced attn store: lane(g,r) -> row q=r, cols 16ct+4g..+3
      *(f32x4*)(arow + kt + 16 * ct) = p;
      // packed bf16 P for PV: [q=r][k=16ct+4g], 8B swizzled write
      u32x2 pk;
      pk[0] = cvtpk(p[0], p[1]);
      pk[1] = cvtpk(p[2], p[3]);
      *(u32x2*)(pb + ((r * 128 + (ct * 16 + 4 * g) * 2) ^ swr)) = pk;
    }
    // PV: oacc += P[16x64] @ V[64x64]
#pragma unroll
    for (int kk2 = 0; kk2 < 2; ++kk2) {
      short8 pa = *(const short8*)(pb + ((r * 128 + kk2 * 64 + g * 16) ^ swr));
#pragma unroll
      for (int ct2 = 0; ct2 < 4; ++ct2) {
        int vrow = ct2 * 16 + r;
        short8 vf = *(const short8*)(bcur + 8192 +
                                     ((vrow * 128 + kk2 * 64 + g * 16) ^ ((vrow & 7) << 4)));
        oacc[ct2] = MFMA16(pa, vf, oacc[ct2]);
      }
    }
    BAR_RAW;
    cur ^= 1;
  }
#pragma unroll
  for (int ct2 = 0; ct2 < 4; ++ct2)
#pragma unroll
    for (int i = 0; i < 4; ++i)
      O[(size_t)(qrow0 + 4 * g + i) * 1024 + h * 64 + ct2 * 16 + r] = f2bf(oacc[ct2][i]);
#undef P1_ISSUE
#undef P2_ISSUE
}

// ---------------------------------------------------------------------------
extern "C" void kernel_launch(void* const* d_in, const int* in_sizes, int n_in,
                              void* d_out, int out_size, void* d_ws, size_t ws_size,
                              hipStream_t stream) {
  const float* q_in = (const float*)d_in[0];
  const float* k_in = (const float*)d_in[1];
  const float* v_in = (const float*)d_in[2];
  const float* wq = (const float*)d_in[3];
  const float* bq = (const float*)d_in[4];
  const float* wk = (const float*)d_in[5];
  const float* bk = (const float*)d_in[6];
  const float* wv = (const float*)d_in[7];
  const float* bv = (const float*)d_in[8];
  const float* wo = (const float*)d_in[9];
  const float* bo = (const float*)d_in[10];

  char* ws = (char*)d_ws;
  const size_t MB8 = 8ull * 1024 * 1024;
  unsigned short* W16 = (unsigned short*)(ws);
  unsigned short* Q16 = (unsigned short*)(ws + MB8);
  unsigned short* K16 = (unsigned short*)(ws + 2 * MB8);
  unsigned short* V16 = (unsigned short*)(ws + 3 * MB8);
  unsigned short* Vt  = (unsigned short*)(ws + 4 * MB8);
  unsigned short* O16 = (unsigned short*)(ws + 3 * MB8);  // alias V16 (dead after transpose)

  float* out = (float*)d_out;
  float* attn = out + 4194304ull;

  dim3 blk(256);
  cast_weights<<<dim3(2048), blk, 0, stream>>>(wq, wk, wv, wo, W16);
  qkv_proj<<<dim3(16, 32, 3), blk, 0, stream>>>(q_in, k_in, v_in, W16, bq, bk, bv, Q16, K16, V16);
  transpose_v<<<dim3(2048), blk, 0, stream>>>(V16, Vt);
  attn_fused<<<dim3(1024), blk, 0, stream>>>(Q16, K16, Vt, attn, O16);
  o_proj<<<dim3(16, 32), blk, 0, stream>>>(O16, W16 + 3145728, bo, out);
}